// Round 7
// baseline (286.203 us; speedup 1.0000x reference)
//
#include <hip/hip_runtime.h>

#define N_TOK 65536
#define DIM   64
#define K_EMB 512
#define BT    256     // tokens per block (16 waves x 16 tokens)
#define NTHR  1024
#define KHALF 256     // codes per B-block (half the codebook)
#define MARGIN 0.125f // > 2x worst-case f16-split sq error (~0.062)

typedef _Float16 half8 __attribute__((ext_vector_type(8)));
typedef _Float16 half4 __attribute__((ext_vector_type(4)));
typedef float    f32x4 __attribute__((ext_vector_type(4)));

// d_out layout (fp32, concatenated in return order):
//   [0)         encodings_ste  N_TOK*DIM   = 4194304
//   [4194304)   idx (as float) N_TOK       = 65536
//   [4259840)   sq_distances   K_EMB*N_TOK = 33554432
//   [37814272)  loss           1
//
// d_ws layout: [0) enorm 512 f32 (2 KB) | [2048) eh f16 codebook [512][64] (64 KB)
//
// R7 = R6 with vq_sqw launched TWICE (idempotent). Differential timing:
//   sqw_us = dur_us(R7) - dur_us(R6); all fixed harness overheads cancel.
// This disambiguates {sqw ~85, argmin ~30} vs {sqw ~30, argmin ~85}, which the
// top-5 counter table cannot (fillBufferAligned ~90us occupies all slots).

// Prep: f16 codebook + fp32 e-norms into ws; zero loss. 32x256 threads.
__global__ void vq_prep(const float* __restrict__ emb,
                        float* __restrict__ enorm,
                        _Float16* __restrict__ eh,
                        float* __restrict__ loss) {
    const int gid = blockIdx.x * blockDim.x + threadIdx.x;   // 8192 threads
    {
        float4 v = ((const float4*)emb)[gid];
        half4 h = { (_Float16)v.x, (_Float16)v.y, (_Float16)v.z, (_Float16)v.w };
        ((half4*)eh)[gid] = h;
    }
    if (gid == 0) *loss = 0.0f;
    if (gid < K_EMB) {
        const float4* e4 = (const float4*)(emb + (size_t)gid * DIM);
        float s = 0.0f;
        #pragma unroll
        for (int i = 0; i < 16; ++i) {
            float4 v = e4[i];
            s += v.x * v.x + v.y * v.y + v.z * v.z + v.w * v.w;
        }
        enorm[gid] = s;
    }
}

// ============================================================================
// KERNEL B: pure sq writer (identical to R6).
// ============================================================================
__global__ __launch_bounds__(NTHR, 8) void vq_sqw(
    const float* __restrict__ x,      // [N_TOK, DIM]
    const float* __restrict__ enorm,  // [K_EMB] fp32 |e|^2
    const _Float16* __restrict__ eh,  // [K_EMB][DIM] f16 codebook
    float* __restrict__ out_sq)
{
    // 32K + 1K + 1K = 34 KB LDS -> 2 blocks/CU
    __shared__ _Float16 eh_s[KHALF * DIM];   // XOR-swizzled: byte ^= ((row&7)<<4)
    __shared__ float en_s[KHALF];
    __shared__ float xn_s[BT];

    const int tid  = threadIdx.x;
    const int bid  = blockIdx.x;            // [0, 512)
    const int cid  = bid & 255;             // token-chunk id
    const int half = bid >> 8;              // code half
    const int k0   = half * KHALF;
    const int chunk = ((cid & 7) << 5) | (cid >> 3);   // XCD-contiguous bijection
    const int n0    = chunk * BT;
    const int lane = tid & 63;
    const int w    = tid >> 6;
    const int lr   = lane & 15;
    const int quad = lane >> 4;
    const int tok  = w * 16 + lr;

    // issue half-codebook loads early
    f32x4 st0, st1;
    {
        const f32x4* g = (const f32x4*)(eh + (size_t)k0 * DIM);  // 2048 x 16B
        st0 = g[tid];
        st1 = g[1024 + tid];
    }
    if (tid < 64) ((float4*)en_s)[tid] = ((const float4*)(enorm + k0))[tid];
    if (tid < BT) {
        // xn: exact quad-pairwise formula (bit-matched to the sq path everywhere)
        const float4* xr = (const float4*)(x + (size_t)(n0 + tid) * DIM);
        float x0 = 0.f, x1 = 0.f, x2 = 0.f, x3 = 0.f;
        #pragma unroll
        for (int c = 0; c < 16; ++c) {
            float4 v = xr[c];
            x0 = fmaf(v.x, v.x, x0);
            x1 = fmaf(v.y, v.y, x1);
            x2 = fmaf(v.z, v.z, x2);
            x3 = fmaf(v.w, v.w, x3);
        }
        xn_s[tid] = (x0 + x1) + (x2 + x3);
    }

    // B-frags: lane owns X[tok][quad*8..+8] and [+32..], f16-split
    half8 bxh0, bxl0, bxh1, bxl1;
    {
        const float4* xrow = (const float4*)(x + (size_t)(n0 + tok) * DIM);
        float4 v0 = xrow[quad * 2];
        float4 v1 = xrow[quad * 2 + 1];
        float4 v2 = xrow[8 + quad * 2];
        float4 v3 = xrow[8 + quad * 2 + 1];
        float f0[8] = { v0.x, v0.y, v0.z, v0.w, v1.x, v1.y, v1.z, v1.w };
        float f1[8] = { v2.x, v2.y, v2.z, v2.w, v3.x, v3.y, v3.z, v3.w };
        #pragma unroll
        for (int i = 0; i < 8; ++i) {
            _Float16 h = (_Float16)f0[i];
            bxh0[i] = h; bxl0[i] = (_Float16)(f0[i] - (float)h);
            _Float16 g = (_Float16)f1[i];
            bxh1[i] = g; bxl1[i] = (_Float16)(f1[i] - (float)g);
        }
    }

    // swizzled ds_write of the half-codebook
    {
        #pragma unroll
        for (int r = 0; r < 2; ++r) {
            const unsigned L = (unsigned)(r * 1024 + tid) * 16u;
            const unsigned d = (L & ~127u) | ((L & 127u) ^ (((L >> 7) & 7u) << 4));
            const f32x4 v = (r == 0) ? st0 : st1;
            *(f32x4*)((char*)eh_s + d) = v;
        }
    }
    __syncthreads();
    const float xnl = xn_s[tok];

    const unsigned sw = (unsigned)(lr & 7) << 4;
    const char* abase = (const char*)eh_s + (unsigned)lr * 128u;
    const unsigned c0 = ((unsigned)(quad * 16)) ^ sw;
    const unsigned c1 = c0 ^ 64u;

    half8 a0 = *(const half8*)(abase + c0);
    half8 a1 = *(const half8*)(abase + c1);

    #pragma unroll 4
    for (int kt = 0; kt < 16; ++kt) {
        const int ktn = kt < 15 ? kt + 1 : 15;
        half8 na0 = *(const half8*)(abase + (unsigned)ktn * 2048u + c0);
        half8 na1 = *(const half8*)(abase + (unsigned)ktn * 2048u + c1);

        f32x4 acc = { 0.f, 0.f, 0.f, 0.f };
        acc = __builtin_amdgcn_mfma_f32_16x16x32_f16(a0, bxh0, acc, 0, 0, 0);
        acc = __builtin_amdgcn_mfma_f32_16x16x32_f16(a1, bxh1, acc, 0, 0, 0);
        acc = __builtin_amdgcn_mfma_f32_16x16x32_f16(a0, bxl0, acc, 0, 0, 0);
        acc = __builtin_amdgcn_mfma_f32_16x16x32_f16(a1, bxl1, acc, 0, 0, 0);

        const f32x4 e4 = *(const f32x4*)&en_s[kt * 16 + quad * 4];
        #pragma unroll
        for (int reg = 0; reg < 4; ++reg) {
            const int   ki = k0 + kt * 16 + quad * 4 + reg;   // global code id
            const float sq = (xnl + e4[reg]) - 2.0f * acc[reg];
            out_sq[(size_t)ki * N_TOK + n0 + tok] = sq;       // free-flow store
        }
        a0 = na0; a1 = na1;
    }
}

// ============================================================================
// KERNEL A: argmin/repair/enc/idx/loss with NO sq stores (identical to R6).
// ============================================================================
__global__ __launch_bounds__(NTHR, 4) void vq_argmin(
    const float* __restrict__ x,      // [N_TOK, DIM]
    const float* __restrict__ emb,    // [K_EMB, DIM] fp32 (exact repair + epilogue)
    const float* __restrict__ enorm,  // [K_EMB] fp32 |e|^2
    const _Float16* __restrict__ eh,  // [K_EMB][DIM] f16 codebook
    float* __restrict__ out_enc,
    float* __restrict__ out_idx,
    float* __restrict__ out_loss)
{
    // 64K + 2K + 1K + 1K + 8K + 1K = 78848 B LDS
    __shared__ _Float16 eh_s[K_EMB * DIM];   // XOR-swizzled: byte ^= ((row&7)<<4)
    __shared__ float en_s[K_EMB];
    __shared__ float xn_s[BT];
    __shared__ int   ccnt[BT];
    __shared__ int   cand[BT * 8];
    __shared__ int   besti[BT];

    const int tid  = threadIdx.x;
    const int bid   = blockIdx.x;
    const int chunk = ((bid & 7) << 5) | (bid >> 3);
    const int n0    = chunk * BT;
    const int lane = tid & 63;
    const int w    = tid >> 6;
    const int lr   = lane & 15;
    const int quad = lane >> 4;
    const int tok  = w * 16 + lr;

    // phase 0a: issue codebook loads early
    f32x4 st0, st1, st2, st3;
    {
        const f32x4* g = (const f32x4*)eh;   // 4096 x 16B chunks
        st0 = g[tid];
        st1 = g[1024 + tid];
        st2 = g[2048 + tid];
        st3 = g[3072 + tid];
    }

    // phase 0b: small staging
    if (tid < 128) ((float4*)en_s)[tid] = ((const float4*)enorm)[tid];
    if (tid < BT) {
        ccnt[tid] = 0;
        const float4* xr = (const float4*)(x + (size_t)(n0 + tid) * DIM);
        float x0 = 0.f, x1 = 0.f, x2 = 0.f, x3 = 0.f;
        #pragma unroll
        for (int c = 0; c < 16; ++c) {
            float4 v = xr[c];
            x0 = fmaf(v.x, v.x, x0);
            x1 = fmaf(v.y, v.y, x1);
            x2 = fmaf(v.z, v.z, x2);
            x3 = fmaf(v.w, v.w, x3);
        }
        xn_s[tid] = (x0 + x1) + (x2 + x3);
    }

    // B-frags
    half8 bxh0, bxl0, bxh1, bxl1;
    {
        const float4* xrow = (const float4*)(x + (size_t)(n0 + tok) * DIM);
        float4 v0 = xrow[quad * 2];
        float4 v1 = xrow[quad * 2 + 1];
        float4 v2 = xrow[8 + quad * 2];
        float4 v3 = xrow[8 + quad * 2 + 1];
        float f0[8] = { v0.x, v0.y, v0.z, v0.w, v1.x, v1.y, v1.z, v1.w };
        float f1[8] = { v2.x, v2.y, v2.z, v2.w, v3.x, v3.y, v3.z, v3.w };
        #pragma unroll
        for (int i = 0; i < 8; ++i) {
            _Float16 h = (_Float16)f0[i];
            bxh0[i] = h; bxl0[i] = (_Float16)(f0[i] - (float)h);
            _Float16 g = (_Float16)f1[i];
            bxh1[i] = g; bxl1[i] = (_Float16)(f1[i] - (float)g);
        }
    }

    // phase 0c: swizzled ds_write of the codebook
    {
        #pragma unroll
        for (int r = 0; r < 4; ++r) {
            const unsigned L = (unsigned)(r * 1024 + tid) * 16u;
            const unsigned d = (L & ~127u) | ((L & 127u) ^ (((L >> 7) & 7u) << 4));
            const f32x4 v = (r == 0) ? st0 : (r == 1) ? st1 : (r == 2) ? st2 : st3;
            *(f32x4*)((char*)eh_s + d) = v;
        }
    }
    __syncthreads();
    const float xnl = xn_s[tok];

    // phase 1: MFMA sweep, min-tracking only (no stores)
    const unsigned sw = (unsigned)(lr & 7) << 4;
    const char* abase = (const char*)eh_s + (unsigned)lr * 128u;
    const unsigned c0 = ((unsigned)(quad * 16)) ^ sw;
    const unsigned c1 = c0 ^ 64u;

    float m1 = 3.4e38f, m2 = 3.4e38f, m3 = 3.4e38f;
    int   i1 = 0, i2 = 0, i3 = 0;

    half8 a0 = *(const half8*)(abase + c0);
    half8 a1 = *(const half8*)(abase + c1);

    for (int kt = 0; kt < 32; ++kt) {
        const int ktn = kt < 31 ? kt + 1 : 31;
        half8 na0 = *(const half8*)(abase + (unsigned)ktn * 2048u + c0);
        half8 na1 = *(const half8*)(abase + (unsigned)ktn * 2048u + c1);

        f32x4 acc = { 0.f, 0.f, 0.f, 0.f };
        acc = __builtin_amdgcn_mfma_f32_16x16x32_f16(a0, bxh0, acc, 0, 0, 0);
        acc = __builtin_amdgcn_mfma_f32_16x16x32_f16(a1, bxh1, acc, 0, 0, 0);
        acc = __builtin_amdgcn_mfma_f32_16x16x32_f16(a0, bxl0, acc, 0, 0, 0);
        acc = __builtin_amdgcn_mfma_f32_16x16x32_f16(a1, bxl1, acc, 0, 0, 0);

        const f32x4 e4 = *(const f32x4*)&en_s[kt * 16 + quad * 4];
        #pragma unroll
        for (int reg = 0; reg < 4; ++reg) {
            const int   ki = kt * 16 + quad * 4 + reg;
            const float sq = (xnl + e4[reg]) - 2.0f * acc[reg];
            // 3-deep running min; ascending ki + strict < keeps first occurrence.
            if (sq < m3) {
                if (sq < m2) {
                    if (sq < m1) { m3 = m2; i3 = i2; m2 = m1; i2 = i1; m1 = sq; i1 = ki; }
                    else         { m3 = m2; i3 = i2; m2 = sq; i2 = ki; }
                } else           { m3 = sq; i3 = ki; }
            }
        }
        a0 = na0; a1 = na1;
    }

    // phase 2: candidates + exact fp32 repair
    float mstar = m1;
    mstar = fminf(mstar, __shfl_xor(mstar, 16, 64));
    mstar = fminf(mstar, __shfl_xor(mstar, 32, 64));
    const float thr = mstar + MARGIN;
    if (m1 <= thr) { int p = atomicAdd(&ccnt[tok], 1); if (p < 8) cand[tok * 8 + p] = i1; }
    if (m2 <= thr) { int p = atomicAdd(&ccnt[tok], 1); if (p < 8) cand[tok * 8 + p] = i2; }
    if (m3 <= thr) { int p = atomicAdd(&ccnt[tok], 1); if (p < 8) cand[tok * 8 + p] = i3; }
    __syncthreads();

    if (tid < BT) {
        const int cnt = min(ccnt[tid], 8);
        float bv = 3.4e38f;
        int   bi = 0x7fffffff;
        const float4* xr = (const float4*)(x + (size_t)(n0 + tid) * DIM);
        for (int c = 0; c < cnt; ++c) {
            const int k = cand[tid * 8 + c];
            const float4* ep = (const float4*)(emb + (size_t)k * DIM);
            float d0 = 0.f, d1 = 0.f, d2 = 0.f, d3 = 0.f;
            #pragma unroll
            for (int j = 0; j < 16; ++j) {
                float4 xv = xr[j], ev = ep[j];
                d0 = fmaf(ev.x, xv.x, d0);
                d1 = fmaf(ev.y, xv.y, d1);
                d2 = fmaf(ev.z, xv.z, d2);
                d3 = fmaf(ev.w, xv.w, d3);
            }
            const float dot = (d0 + d1) + (d2 + d3);
            const float sq  = (xn_s[tid] + en_s[k]) - 2.0f * dot;
            if (sq < bv || (sq == bv && k < bi)) { bv = sq; bi = k; }
        }
        besti[tid] = bi;
        out_idx[n0 + tid] = (float)bi;   // <= 511: exact in fp32
    }
    __syncthreads();

    // phase 3: enc/ste + loss
    float lp = 0.0f;
    {
        const int c = (tid & 15) * 4;
        const int r = tid >> 4;          // 0..63
        #pragma unroll
        for (int p = 0; p < 4; ++p) {
            const int rr = r + 64 * p;   // 0..255
            const int bi = besti[rr];
            float4 e  = *(const float4*)&emb[(size_t)bi * DIM + c];
            *(float4*)&out_enc[(size_t)(n0 + rr) * DIM + c] = e;
            float4 xv = *(const float4*)&x[(size_t)(n0 + rr) * DIM + c];
            const float d0 = e.x - xv.x, d1 = e.y - xv.y, d2 = e.z - xv.z, d3 = e.w - xv.w;
            lp += d0 * d0 + d1 * d1 + d2 * d2 + d3 * d3;
        }
    }
    #pragma unroll
    for (int off = 32; off > 0; off >>= 1) lp += __shfl_down(lp, off, 64);
    if ((tid & 63) == 0) {
        atomicAdd(out_loss, lp * (1.25f / 4194304.0f));  // (1+beta)*mean, beta=0.25
    }
}

extern "C" void kernel_launch(void* const* d_in, const int* in_sizes, int n_in,
                              void* d_out, int out_size, void* d_ws, size_t ws_size,
                              hipStream_t stream) {
    const float* x   = (const float*)d_in[0];
    const float* emb = (const float*)d_in[1];
    float* out       = (float*)d_out;
    float* enorm     = (float*)d_ws;                       // 512 f32
    _Float16* eh     = (_Float16*)((char*)d_ws + 2048);    // 512*64 f16 (64 KB)

    float* out_enc  = out;                // 4194304
    float* out_idx  = out + 4194304;      // 65536
    float* out_sq   = out + 4259840;      // 33554432
    float* out_loss = out + 37814272;     // 1

    vq_prep<<<32, 256, 0, stream>>>(emb, enorm, eh, out_loss);
    // Launched TWICE (idempotent): dur_us(R7) - dur_us(R6) == sqw duration.
    vq_sqw<<<512, NTHR, 0, stream>>>(x, enorm, eh, out_sq);
    vq_sqw<<<512, NTHR, 0, stream>>>(x, enorm, eh, out_sq);
    vq_argmin<<<N_TOK / BT, NTHR, 0, stream>>>(x, emb, enorm, eh,
                                               out_enc, out_idx, out_loss);
}

// Round 9
// 180.848 us; speedup vs baseline: 1.5826x; 1.5826x over previous
//
#include <hip/hip_runtime.h>

#define N_TOK 65536
#define DIM   64
#define K_EMB 512
#define BT    256     // tokens per block (16 waves x 16 tokens)
#define NTHR  1024
#define MARGIN 0.125f // > 2x worst-case f16-split sq error (~0.062)

typedef _Float16 half8 __attribute__((ext_vector_type(8)));
typedef _Float16 half4 __attribute__((ext_vector_type(4)));
typedef float    f32x4 __attribute__((ext_vector_type(4)));

// d_out layout (fp32, concatenated in return order):
//   [0)         encodings_ste  N_TOK*DIM   = 4194304
//   [4194304)   idx (as float) N_TOK       = 65536
//   [4259840)   sq_distances   K_EMB*N_TOK = 33554432
//   [37814272)  loss           1
//
// d_ws layout: [0) enorm 512 f32 (2 KB) | [2048) eh f16 codebook [512][64] (64 KB)
//
// R8 finding (differential, R6/R7): the ~92us invariant of R0-R5 was NOT the
// store stream (pure-store kernel: 36us ~ 4TB/s) but the loss epilogue's
// 4096 same-address device-scope atomicAdds (16/block x 256 blocks), a
// serialized cross-XCD tail of ~80us during which all pipes idle. Fix: block
// reduction in LDS -> ONE atomicAdd per block (256 total).
// (R8 bench was an infra failure -- container acquisition -- resubmitted as R9.)

// Prep: f16 codebook + fp32 e-norms into ws; zero loss. 32x256 threads.
__global__ void vq_prep(const float* __restrict__ emb,
                        float* __restrict__ enorm,
                        _Float16* __restrict__ eh,
                        float* __restrict__ loss) {
    const int gid = blockIdx.x * blockDim.x + threadIdx.x;   // 8192 threads
    {
        float4 v = ((const float4*)emb)[gid];
        half4 h = { (_Float16)v.x, (_Float16)v.y, (_Float16)v.z, (_Float16)v.w };
        ((half4*)eh)[gid] = h;
    }
    if (gid == 0) *loss = 0.0f;
    if (gid < K_EMB) {
        const float4* e4 = (const float4*)(emb + (size_t)gid * DIM);
        float s = 0.0f;
        #pragma unroll
        for (int i = 0; i < 16; ++i) {
            float4 v = e4[i];
            s += v.x * v.x + v.y * v.y + v.z * v.z + v.w * v.w;
        }
        enorm[gid] = s;
    }
}

__global__ __launch_bounds__(NTHR, 4) void vq_main(
    const float* __restrict__ x,      // [N_TOK, DIM]
    const float* __restrict__ emb,    // [K_EMB, DIM] fp32 (exact repair + epilogue)
    const float* __restrict__ enorm,  // [K_EMB] fp32 |e|^2
    const _Float16* __restrict__ eh,  // [K_EMB][DIM] f16 codebook
    float* __restrict__ out_enc,
    float* __restrict__ out_idx,
    float* __restrict__ out_sq,
    float* __restrict__ out_loss)
{
    // 64K + 2K + 1K + 1K + 8K + 1K + 64B LDS
    __shared__ _Float16 eh_s[K_EMB * DIM];   // XOR-swizzled: byte ^= ((row&7)<<4)
    __shared__ float en_s[K_EMB];
    __shared__ float xn_s[BT];
    __shared__ int   ccnt[BT];
    __shared__ int   cand[BT * 8];
    __shared__ int   besti[BT];
    __shared__ float lsum[16];

    const int tid  = threadIdx.x;
    // bijective XCD-contiguous chunk swizzle (256 blocks, 8 XCDs, 32 chunks/XCD)
    const int bid   = blockIdx.x;
    const int chunk = ((bid & 7) << 5) | (bid >> 3);
    const int n0    = chunk * BT;
    const int lane = tid & 63;
    const int w    = tid >> 6;      // wave id = 16-token tile (0..15)
    const int lr   = lane & 15;
    const int quad = lane >> 4;
    const int tok  = w * 16 + lr;

    // ====== phase 0a: issue codebook loads early (64 B/thread, 64 KB/block) ======
    f32x4 st0, st1, st2, st3;
    {
        const f32x4* g = (const f32x4*)eh;   // 4096 x 16B chunks
        st0 = g[tid];
        st1 = g[1024 + tid];
        st2 = g[2048 + tid];
        st3 = g[3072 + tid];
    }

    // ====== phase 0b: small staging (latency of 0a hides under this) ======
    if (tid < 128) ((float4*)en_s)[tid] = ((const float4*)enorm)[tid];
    if (tid < BT) {
        ccnt[tid] = 0;
        // xn with the exact quad-pairwise formula (bit-matched to the repair path).
        const float4* xr = (const float4*)(x + (size_t)(n0 + tid) * DIM);
        float x0 = 0.f, x1 = 0.f, x2 = 0.f, x3 = 0.f;
        #pragma unroll
        for (int c = 0; c < 16; ++c) {
            float4 v = xr[c];
            x0 = fmaf(v.x, v.x, x0);
            x1 = fmaf(v.y, v.y, x1);
            x2 = fmaf(v.z, v.z, x2);
            x3 = fmaf(v.w, v.w, x3);
        }
        xn_s[tid] = (x0 + x1) + (x2 + x3);
    }

    // ---- B-frags straight from global: lane owns X[tok][quad*8..+8] and [+32..] ----
    half8 bxh0, bxl0, bxh1, bxl1;
    {
        const float4* xrow = (const float4*)(x + (size_t)(n0 + tok) * DIM);
        float4 v0 = xrow[quad * 2];
        float4 v1 = xrow[quad * 2 + 1];
        float4 v2 = xrow[8 + quad * 2];
        float4 v3 = xrow[8 + quad * 2 + 1];
        float f0[8] = { v0.x, v0.y, v0.z, v0.w, v1.x, v1.y, v1.z, v1.w };
        float f1[8] = { v2.x, v2.y, v2.z, v2.w, v3.x, v3.y, v3.z, v3.w };
        #pragma unroll
        for (int i = 0; i < 8; ++i) {
            _Float16 h = (_Float16)f0[i];
            bxh0[i] = h; bxl0[i] = (_Float16)(f0[i] - (float)h);
            _Float16 g = (_Float16)f1[i];
            bxh1[i] = g; bxl1[i] = (_Float16)(f1[i] - (float)g);
        }
    }

    // ====== phase 0c: swizzled ds_write of the codebook ======
    // lds[row*128 + (col ^ ((row&7)<<4))] = eh[row*128 + col]  (involution)
    {
        #pragma unroll
        for (int r = 0; r < 4; ++r) {
            const unsigned L = (unsigned)(r * 1024 + tid) * 16u;
            const unsigned d = (L & ~127u) | ((L & 127u) ^ (((L >> 7) & 7u) << 4));
            const f32x4 v = (r == 0) ? st0 : (r == 1) ? st1 : (r == 2) ? st2 : st3;
            *(f32x4*)((char*)eh_s + d) = v;
        }
    }
    __syncthreads();
    const float xnl = xn_s[tok];

    // ================= phase 1: MFMA sweep (A from swizzled LDS) =================
    // A frag: lane holds E[code = kt*16 + lr][k = quad*8 + j]
    // C frag: lane reg holds D[code = kt*16 + quad*4 + reg][token = tok]
    const unsigned sw = (unsigned)(lr & 7) << 4;
    const char* abase = (const char*)eh_s + (unsigned)lr * 128u;
    const unsigned c0 = ((unsigned)(quad * 16)) ^ sw;
    const unsigned c1 = c0 ^ 64u;   // == ((quad*16+64) ^ sw)

    float m1 = 3.4e38f, m2 = 3.4e38f, m3 = 3.4e38f;
    int   i1 = 0, i2 = 0, i3 = 0;

    half8 a0 = *(const half8*)(abase + c0);
    half8 a1 = *(const half8*)(abase + c1);

    for (int kt = 0; kt < 32; ++kt) {
        // prefetch next tile's A-frags from LDS (clamped re-read of last tile)
        const int ktn = kt < 31 ? kt + 1 : 31;
        half8 na0 = *(const half8*)(abase + (unsigned)ktn * 2048u + c0);
        half8 na1 = *(const half8*)(abase + (unsigned)ktn * 2048u + c1);

        f32x4 acc = { 0.f, 0.f, 0.f, 0.f };
        acc = __builtin_amdgcn_mfma_f32_16x16x32_f16(a0, bxh0, acc, 0, 0, 0);
        acc = __builtin_amdgcn_mfma_f32_16x16x32_f16(a1, bxh1, acc, 0, 0, 0);
        acc = __builtin_amdgcn_mfma_f32_16x16x32_f16(a0, bxl0, acc, 0, 0, 0);
        acc = __builtin_amdgcn_mfma_f32_16x16x32_f16(a1, bxl1, acc, 0, 0, 0);

        const f32x4 e4 = *(const f32x4*)&en_s[kt * 16 + quad * 4];
        #pragma unroll
        for (int reg = 0; reg < 4; ++reg) {
            const int   ki = kt * 16 + quad * 4 + reg;
            const float sq = (xnl + e4[reg]) - 2.0f * acc[reg];
            out_sq[(size_t)ki * N_TOK + n0 + tok] = sq;   // free-flow store
            // 3-deep running min; ascending ki + strict < keeps first occurrence.
            if (sq < m3) {
                if (sq < m2) {
                    if (sq < m1) { m3 = m2; i3 = i2; m2 = m1; i2 = i1; m1 = sq; i1 = ki; }
                    else         { m3 = m2; i3 = i2; m2 = sq; i2 = ki; }
                } else           { m3 = sq; i3 = ki; }
            }
        }
        a0 = na0; a1 = na1;
    }

    // ================= phase 2: candidates + exact fp32 repair =================
    float mstar = m1;
    mstar = fminf(mstar, __shfl_xor(mstar, 16, 64));
    mstar = fminf(mstar, __shfl_xor(mstar, 32, 64));
    const float thr = mstar + MARGIN;
    if (m1 <= thr) { int p = atomicAdd(&ccnt[tok], 1); if (p < 8) cand[tok * 8 + p] = i1; }
    if (m2 <= thr) { int p = atomicAdd(&ccnt[tok], 1); if (p < 8) cand[tok * 8 + p] = i2; }
    if (m3 <= thr) { int p = atomicAdd(&ccnt[tok], 1); if (p < 8) cand[tok * 8 + p] = i3; }
    __syncthreads();

    if (tid < BT) {
        const int cnt = min(ccnt[tid], 8);
        float bv = 3.4e38f;
        int   bi = 0x7fffffff;
        const float4* xr = (const float4*)(x + (size_t)(n0 + tid) * DIM);
        for (int c = 0; c < cnt; ++c) {
            const int k = cand[tid * 8 + c];
            const float4* ep = (const float4*)(emb + (size_t)k * DIM);
            // exact fp32 recompute, bit-identical to the passing arithmetic
            float d0 = 0.f, d1 = 0.f, d2 = 0.f, d3 = 0.f;
            #pragma unroll
            for (int j = 0; j < 16; ++j) {
                float4 xv = xr[j], ev = ep[j];
                d0 = fmaf(ev.x, xv.x, d0);
                d1 = fmaf(ev.y, xv.y, d1);
                d2 = fmaf(ev.z, xv.z, d2);
                d3 = fmaf(ev.w, xv.w, d3);
            }
            const float dot = (d0 + d1) + (d2 + d3);
            const float sq  = (xn_s[tid] + en_s[k]) - 2.0f * dot;
            if (sq < bv || (sq == bv && k < bi)) { bv = sq; bi = k; }
        }
        besti[tid] = bi;
        out_idx[n0 + tid] = (float)bi;   // <= 511: exact in fp32
    }
    __syncthreads();

    // ================= phase 3: enc/ste + loss =================
    float lp = 0.0f;
    {
        const int c = (tid & 15) * 4;
        const int r = tid >> 4;          // 0..63
        #pragma unroll
        for (int p = 0; p < 4; ++p) {
            const int rr = r + 64 * p;   // 0..255
            const int bi = besti[rr];
            float4 e  = *(const float4*)&emb[(size_t)bi * DIM + c];
            *(float4*)&out_enc[(size_t)(n0 + rr) * DIM + c] = e;
            float4 xv = *(const float4*)&x[(size_t)(n0 + rr) * DIM + c];
            const float d0 = e.x - xv.x, d1 = e.y - xv.y, d2 = e.z - xv.z, d3 = e.w - xv.w;
            lp += d0 * d0 + d1 * d1 + d2 * d2 + d3 * d3;
        }
    }
    #pragma unroll
    for (int off = 32; off > 0; off >>= 1) lp += __shfl_down(lp, off, 64);
    // R8 FIX: block-reduce loss partials in LDS -> ONE device atomic per block
    // (was 16/block = 4096 same-address cross-XCD atomics = ~80us serialized tail)
    if (lane == 0) lsum[w] = lp;
    __syncthreads();
    if (tid == 0) {
        float s = 0.0f;
        #pragma unroll
        for (int i = 0; i < 16; ++i) s += lsum[i];
        atomicAdd(out_loss, s * (1.25f / 4194304.0f));  // (1+beta)*mean, beta=0.25
    }
}

extern "C" void kernel_launch(void* const* d_in, const int* in_sizes, int n_in,
                              void* d_out, int out_size, void* d_ws, size_t ws_size,
                              hipStream_t stream) {
    const float* x   = (const float*)d_in[0];
    const float* emb = (const float*)d_in[1];
    float* out       = (float*)d_out;
    float* enorm     = (float*)d_ws;                       // 512 f32
    _Float16* eh     = (_Float16*)((char*)d_ws + 2048);    // 512*64 f16 (64 KB)

    float* out_enc  = out;                // 4194304
    float* out_idx  = out + 4194304;      // 65536
    float* out_sq   = out + 4259840;      // 33554432
    float* out_loss = out + 37814272;     // 1

    vq_prep<<<32, 256, 0, stream>>>(emb, enorm, eh, out_loss);
    vq_main<<<N_TOK / BT, NTHR, 0, stream>>>(x, emb, enorm, eh,
                                             out_enc, out_idx, out_sq, out_loss);
}

// Round 10
// 176.489 us; speedup vs baseline: 1.6217x; 1.0247x over previous
//
#include <hip/hip_runtime.h>

#define N_TOK 65536
#define DIM   64
#define K_EMB 512
#define BT    128     // tokens per block (8 waves x 16)
#define NTHR  512
#define MARGIN 0.125f // > 2x worst-case f16-split sq error (~0.062)

typedef _Float16 half8 __attribute__((ext_vector_type(8)));
typedef _Float16 half4 __attribute__((ext_vector_type(4)));
typedef float    f32x4 __attribute__((ext_vector_type(4)));

// d_out layout (fp32, concatenated in return order):
//   [0)         encodings_ste  N_TOK*DIM   = 4194304
//   [4194304)   idx (as float) N_TOK       = 65536
//   [4259840)   sq_distances   K_EMB*N_TOK = 33554432
//   [37814272)  loss           1
//
// d_ws layout: [0) enorm 512 f32 (2 KB) | [2048) eh f16 codebook [512][64] (64 KB)
//
// R9 confirmed (dur 225.6->180.8): the R0-R5 ~92us invariant was the loss
// epilogue's 4096 same-address device atomics; 1 atomic/block fixed it
// (vq_main ~50us). R10: the remaining gap vs the R6/R7 differential floor
// (full traffic = 35.6us at 2 blocks/CU) is GRID-limited concurrency -- 256
// blocks on 256 CUs = 1 block/CU, so stores run at half concurrency and the
// serial repair/epilogue phases have no co-resident block to hide under.
// Change: BT 256->128, 512 blocks = exactly 2 blocks/CU (LDS 71.6KB x2 fits).

// Prep: f16 codebook + fp32 e-norms into ws; zero loss. 32x256 threads.
__global__ void vq_prep(const float* __restrict__ emb,
                        float* __restrict__ enorm,
                        _Float16* __restrict__ eh,
                        float* __restrict__ loss) {
    const int gid = blockIdx.x * blockDim.x + threadIdx.x;   // 8192 threads
    {
        float4 v = ((const float4*)emb)[gid];
        half4 h = { (_Float16)v.x, (_Float16)v.y, (_Float16)v.z, (_Float16)v.w };
        ((half4*)eh)[gid] = h;
    }
    if (gid == 0) *loss = 0.0f;
    if (gid < K_EMB) {
        const float4* e4 = (const float4*)(emb + (size_t)gid * DIM);
        float s = 0.0f;
        #pragma unroll
        for (int i = 0; i < 16; ++i) {
            float4 v = e4[i];
            s += v.x * v.x + v.y * v.y + v.z * v.z + v.w * v.w;
        }
        enorm[gid] = s;
    }
}

__global__ __launch_bounds__(NTHR, 4) void vq_main(
    const float* __restrict__ x,      // [N_TOK, DIM]
    const float* __restrict__ emb,    // [K_EMB, DIM] fp32 (exact repair + epilogue)
    const float* __restrict__ enorm,  // [K_EMB] fp32 |e|^2
    const _Float16* __restrict__ eh,  // [K_EMB][DIM] f16 codebook
    float* __restrict__ out_enc,
    float* __restrict__ out_idx,
    float* __restrict__ out_sq,
    float* __restrict__ out_loss)
{
    // 64K + 2K + 0.5K + 0.5K + 4K + 0.5K + 32B = ~71.6 KB -> 2 blocks/CU
    __shared__ _Float16 eh_s[K_EMB * DIM];   // XOR-swizzled: byte ^= ((row&7)<<4)
    __shared__ float en_s[K_EMB];
    __shared__ float xn_s[BT];
    __shared__ int   ccnt[BT];
    __shared__ int   cand[BT * 8];
    __shared__ int   besti[BT];
    __shared__ float lsum[8];

    const int tid  = threadIdx.x;
    // bijective XCD-contiguous chunk swizzle (512 blocks, 8 XCDs, 64 chunks/XCD)
    const int bid   = blockIdx.x;
    const int chunk = ((bid & 7) << 6) | (bid >> 3);
    const int n0    = chunk * BT;
    const int lane = tid & 63;
    const int w    = tid >> 6;      // wave id = 16-token tile (0..7)
    const int lr   = lane & 15;
    const int quad = lane >> 4;
    const int tok  = w * 16 + lr;

    // ====== phase 0a: issue codebook loads early (128 B/thread, 64 KB/block) ======
    f32x4 st[8];
    {
        const f32x4* g = (const f32x4*)eh;   // 4096 x 16B chunks
        #pragma unroll
        for (int r = 0; r < 8; ++r) st[r] = g[r * NTHR + tid];
    }

    // ====== phase 0b: small staging (latency of 0a hides under this) ======
    if (tid < 128) ((float4*)en_s)[tid] = ((const float4*)enorm)[tid];
    if (tid < BT) {
        ccnt[tid] = 0;
        // xn with the exact quad-pairwise formula (bit-matched to the repair path).
        const float4* xr = (const float4*)(x + (size_t)(n0 + tid) * DIM);
        float x0 = 0.f, x1 = 0.f, x2 = 0.f, x3 = 0.f;
        #pragma unroll
        for (int c = 0; c < 16; ++c) {
            float4 v = xr[c];
            x0 = fmaf(v.x, v.x, x0);
            x1 = fmaf(v.y, v.y, x1);
            x2 = fmaf(v.z, v.z, x2);
            x3 = fmaf(v.w, v.w, x3);
        }
        xn_s[tid] = (x0 + x1) + (x2 + x3);
    }

    // ---- B-frags straight from global: lane owns X[tok][quad*8..+8] and [+32..] ----
    half8 bxh0, bxl0, bxh1, bxl1;
    {
        const float4* xrow = (const float4*)(x + (size_t)(n0 + tok) * DIM);
        float4 v0 = xrow[quad * 2];
        float4 v1 = xrow[quad * 2 + 1];
        float4 v2 = xrow[8 + quad * 2];
        float4 v3 = xrow[8 + quad * 2 + 1];
        float f0[8] = { v0.x, v0.y, v0.z, v0.w, v1.x, v1.y, v1.z, v1.w };
        float f1[8] = { v2.x, v2.y, v2.z, v2.w, v3.x, v3.y, v3.z, v3.w };
        #pragma unroll
        for (int i = 0; i < 8; ++i) {
            _Float16 h = (_Float16)f0[i];
            bxh0[i] = h; bxl0[i] = (_Float16)(f0[i] - (float)h);
            _Float16 g = (_Float16)f1[i];
            bxh1[i] = g; bxl1[i] = (_Float16)(f1[i] - (float)g);
        }
    }

    // ====== phase 0c: swizzled ds_write of the codebook ======
    // lds[row*128 + (col ^ ((row&7)<<4))] = eh[row*128 + col]  (involution)
    {
        #pragma unroll
        for (int r = 0; r < 8; ++r) {
            const unsigned L = (unsigned)(r * NTHR + tid) * 16u;
            const unsigned d = (L & ~127u) | ((L & 127u) ^ (((L >> 7) & 7u) << 4));
            *(f32x4*)((char*)eh_s + d) = st[r];
        }
    }
    __syncthreads();
    const float xnl = xn_s[tok];

    // ================= phase 1: MFMA sweep (A from swizzled LDS) =================
    // A frag: lane holds E[code = kt*16 + lr][k = quad*8 + j]
    // C frag: lane reg holds D[code = kt*16 + quad*4 + reg][token = tok]
    const unsigned sw = (unsigned)(lr & 7) << 4;
    const char* abase = (const char*)eh_s + (unsigned)lr * 128u;
    const unsigned c0 = ((unsigned)(quad * 16)) ^ sw;
    const unsigned c1 = c0 ^ 64u;   // == ((quad*16+64) ^ sw)

    float m1 = 3.4e38f, m2 = 3.4e38f, m3 = 3.4e38f;
    int   i1 = 0, i2 = 0, i3 = 0;

    half8 a0 = *(const half8*)(abase + c0);
    half8 a1 = *(const half8*)(abase + c1);

    for (int kt = 0; kt < 32; ++kt) {
        // prefetch next tile's A-frags from LDS (clamped re-read of last tile)
        const int ktn = kt < 31 ? kt + 1 : 31;
        half8 na0 = *(const half8*)(abase + (unsigned)ktn * 2048u + c0);
        half8 na1 = *(const half8*)(abase + (unsigned)ktn * 2048u + c1);

        f32x4 acc = { 0.f, 0.f, 0.f, 0.f };
        acc = __builtin_amdgcn_mfma_f32_16x16x32_f16(a0, bxh0, acc, 0, 0, 0);
        acc = __builtin_amdgcn_mfma_f32_16x16x32_f16(a1, bxh1, acc, 0, 0, 0);
        acc = __builtin_amdgcn_mfma_f32_16x16x32_f16(a0, bxl0, acc, 0, 0, 0);
        acc = __builtin_amdgcn_mfma_f32_16x16x32_f16(a1, bxl1, acc, 0, 0, 0);

        const f32x4 e4 = *(const f32x4*)&en_s[kt * 16 + quad * 4];
        #pragma unroll
        for (int reg = 0; reg < 4; ++reg) {
            const int   ki = kt * 16 + quad * 4 + reg;
            const float sq = (xnl + e4[reg]) - 2.0f * acc[reg];
            out_sq[(size_t)ki * N_TOK + n0 + tok] = sq;   // free-flow store
            // 3-deep running min; ascending ki + strict < keeps first occurrence.
            if (sq < m3) {
                if (sq < m2) {
                    if (sq < m1) { m3 = m2; i3 = i2; m2 = m1; i2 = i1; m1 = sq; i1 = ki; }
                    else         { m3 = m2; i3 = i2; m2 = sq; i2 = ki; }
                } else           { m3 = sq; i3 = ki; }
            }
        }
        a0 = na0; a1 = na1;
    }

    // ================= phase 2: candidates + exact fp32 repair =================
    float mstar = m1;
    mstar = fminf(mstar, __shfl_xor(mstar, 16, 64));
    mstar = fminf(mstar, __shfl_xor(mstar, 32, 64));
    const float thr = mstar + MARGIN;
    if (m1 <= thr) { int p = atomicAdd(&ccnt[tok], 1); if (p < 8) cand[tok * 8 + p] = i1; }
    if (m2 <= thr) { int p = atomicAdd(&ccnt[tok], 1); if (p < 8) cand[tok * 8 + p] = i2; }
    if (m3 <= thr) { int p = atomicAdd(&ccnt[tok], 1); if (p < 8) cand[tok * 8 + p] = i3; }
    __syncthreads();

    if (tid < BT) {
        const int cnt = min(ccnt[tid], 8);
        float bv = 3.4e38f;
        int   bi = 0x7fffffff;
        const float4* xr = (const float4*)(x + (size_t)(n0 + tid) * DIM);
        for (int c = 0; c < cnt; ++c) {
            const int k = cand[tid * 8 + c];
            const float4* ep = (const float4*)(emb + (size_t)k * DIM);
            // exact fp32 recompute, bit-identical to the passing arithmetic
            float d0 = 0.f, d1 = 0.f, d2 = 0.f, d3 = 0.f;
            #pragma unroll
            for (int j = 0; j < 16; ++j) {
                float4 xv = xr[j], ev = ep[j];
                d0 = fmaf(ev.x, xv.x, d0);
                d1 = fmaf(ev.y, xv.y, d1);
                d2 = fmaf(ev.z, xv.z, d2);
                d3 = fmaf(ev.w, xv.w, d3);
            }
            const float dot = (d0 + d1) + (d2 + d3);
            const float sq  = (xn_s[tid] + en_s[k]) - 2.0f * dot;
            if (sq < bv || (sq == bv && k < bi)) { bv = sq; bi = k; }
        }
        besti[tid] = bi;
        out_idx[n0 + tid] = (float)bi;   // <= 511: exact in fp32
    }
    __syncthreads();

    // ================= phase 3: enc/ste + loss =================
    float lp = 0.0f;
    {
        const int c = (tid & 15) * 4;
        const int r = tid >> 4;          // 0..31
        #pragma unroll
        for (int p = 0; p < 4; ++p) {
            const int rr = r + 32 * p;   // 0..127
            const int bi = besti[rr];
            float4 e  = *(const float4*)&emb[(size_t)bi * DIM + c];
            *(float4*)&out_enc[(size_t)(n0 + rr) * DIM + c] = e;
            float4 xv = *(const float4*)&x[(size_t)(n0 + rr) * DIM + c];
            const float d0 = e.x - xv.x, d1 = e.y - xv.y, d2 = e.z - xv.z, d3 = e.w - xv.w;
            lp += d0 * d0 + d1 * d1 + d2 * d2 + d3 * d3;
        }
    }
    #pragma unroll
    for (int off = 32; off > 0; off >>= 1) lp += __shfl_down(lp, off, 64);
    // ONE device atomic per block (512 total)
    if (lane == 0) lsum[w] = lp;
    __syncthreads();
    if (tid == 0) {
        float s = 0.0f;
        #pragma unroll
        for (int i = 0; i < 8; ++i) s += lsum[i];
        atomicAdd(out_loss, s * (1.25f / 4194304.0f));  // (1+beta)*mean, beta=0.25
    }
}

extern "C" void kernel_launch(void* const* d_in, const int* in_sizes, int n_in,
                              void* d_out, int out_size, void* d_ws, size_t ws_size,
                              hipStream_t stream) {
    const float* x   = (const float*)d_in[0];
    const float* emb = (const float*)d_in[1];
    float* out       = (float*)d_out;
    float* enorm     = (float*)d_ws;                       // 512 f32
    _Float16* eh     = (_Float16*)((char*)d_ws + 2048);    // 512*64 f16 (64 KB)

    float* out_enc  = out;                // 4194304
    float* out_idx  = out + 4194304;      // 65536
    float* out_sq   = out + 4259840;      // 33554432
    float* out_loss = out + 37814272;     // 1

    vq_prep<<<32, 256, 0, stream>>>(emb, enorm, eh, out_loss);
    vq_main<<<N_TOK / BT, NTHR, 0, stream>>>(x, emb, enorm, eh,
                                             out_enc, out_idx, out_sq, out_loss);
}